// Round 1
// baseline (165.341 us; speedup 1.0000x reference)
//
#include <hip/hip_runtime.h>
#include <hip/hip_bf16.h>
#include <math.h>

#define LRELU_ALPHA 0.2f
#define UPB 32  // u's processed per wave in wh_kernel

__device__ __forceinline__ float lane_bcast(float v, int lane) {
    return __uint_as_float((unsigned)__builtin_amdgcn_readlane((int)__float_as_uint(v), lane));
}

// Kernel 1: Wh[h][u][o] = sum_d embed[u][d] * W[h][d][o]  (embed = nf[unique_nodes[u]])
// plus the 4 score dots per (h,u): {a_pos_dst, a_pos_src, a_neg_dst, a_neg_src} . Wh[h][u][:]
__global__ __launch_bounds__(256) void wh_kernel(
    const float* __restrict__ nf, const float* __restrict__ W,
    const float* __restrict__ a_pos, const float* __restrict__ a_neg,
    const int* __restrict__ unique_nodes,
    __hip_bfloat16* __restrict__ WhB, float4* __restrict__ sc, int U)
{
    const int h    = blockIdx.y;
    const int wave = threadIdx.x >> 6;
    const int lane = threadIdx.x & 63;

    // W[h][:, lane] into registers (reused across UPB nodes)
    const float* Wh_ = W + (size_t)h * 64 * 64;
    float Wreg[64];
#pragma unroll
    for (int d = 0; d < 64; ++d) Wreg[d] = Wh_[d * 64 + lane];

    const float apd  = a_pos[h * 128 + lane];
    const float aps  = a_pos[h * 128 + 64 + lane];
    const float andv = a_neg[h * 128 + lane];
    const float ansv = a_neg[h * 128 + 64 + lane];

    const long u0 = ((long)blockIdx.x * 4 + wave) * UPB;
    for (int t = 0; t < UPB; ++t) {
        const long u = u0 + t;
        if (u >= U) return;
        const int g = unique_nodes[u];
        const float ev = nf[(size_t)g * 64 + lane];   // embed[u][lane]
        float acc = 0.f;
#pragma unroll
        for (int d = 0; d < 64; ++d) {
            acc = fmaf(lane_bcast(ev, d), Wreg[d], acc);
        }
        // 4 score dots via butterfly reduction over 64 lanes
        float d0 = acc * apd, d1 = acc * aps, d2 = acc * andv, d3 = acc * ansv;
#pragma unroll
        for (int off = 32; off; off >>= 1) {
            d0 += __shfl_xor(d0, off, 64);
            d1 += __shfl_xor(d1, off, 64);
            d2 += __shfl_xor(d2, off, 64);
            d3 += __shfl_xor(d3, off, 64);
        }
        WhB[((size_t)h * U + u) * 64 + lane] = __float2bfloat16(acc);
        if (lane == 0) sc[(size_t)h * U + u] = make_float4(d0, d1, d2, d3);
    }
}

// Kernel 2: per (row, head) wave: 33-edge joint softmax + weighted gather-sum.
// Edge layout (from setup_inputs): lane<DEGP -> pos edge, lane==DEGP -> self edge
// (pos_col[N*DEGP + i]), else neg edge.
__global__ __launch_bounds__(256) void agg_kernel(
    const int* __restrict__ row_unique,
    const int* __restrict__ pos_col, const int* __restrict__ neg_col,
    const __hip_bfloat16* __restrict__ WhB, const float4* __restrict__ sc,
    float* __restrict__ out, int N, int U, int DEGP, int DEGN, int H)
{
    const int i    = blockIdx.x;
    const int h    = threadIdx.x >> 6;
    const int lane = threadIdx.x & 63;
    const int NE   = DEGP + 1 + DEGN;   // 33

    __shared__ int   s_col[64];
    __shared__ float s_att[8][64];

    const float4* sch = sc + (size_t)h * U;
    const float4 scd = sch[row_unique[i]];   // .x = pos_dst, .z = neg_dst

    int col = 0;
    float score = -INFINITY;
    if (lane < NE) {
        if (lane < DEGP)       col = pos_col[(size_t)i * DEGP + lane];
        else if (lane == DEGP) col = pos_col[(size_t)N * DEGP + i];  // self edge
        else                   col = neg_col[(size_t)i * DEGN + (lane - DEGP - 1)];
        const float4 scs = sch[col];         // .y = pos_src, .w = neg_src
        const float raw = (lane <= DEGP) ? (scd.x + scs.y) : (scd.z + scs.w);
        score = (raw > 0.f) ? raw : LRELU_ALPHA * raw;
    }
    // joint softmax over the 33 active lanes
    float m = score;
#pragma unroll
    for (int off = 32; off; off >>= 1) m = fmaxf(m, __shfl_xor(m, off, 64));
    const float ex = (lane < NE) ? __expf(score - m) : 0.f;
    float ssum = ex;
#pragma unroll
    for (int off = 32; off; off >>= 1) ssum += __shfl_xor(ssum, off, 64);
    const float att = ex / ssum;

    if (h == 0) s_col[lane] = col;
    s_att[h][lane] = att;
    __syncthreads();

    const __hip_bfloat16* wh = WhB + (size_t)h * U * 64;
    float acc = 0.f;
    for (int e = 0; e < NE; ++e) {
        const int   c = s_col[e];
        const float a = s_att[h][e];
        acc = fmaf(a, __bfloat162float(wh[(size_t)c * 64 + lane]), acc);
    }
    out[(size_t)i * (H * 64) + h * 64 + lane] = fmaxf(acc, 0.f);
}

// Kernel 3: edge_out = edge_embedding @ edge_transform  ([ET,64] @ [64,64])
__global__ void edge_kernel(const float* __restrict__ ee, const float* __restrict__ et,
                            float* __restrict__ out, int ET)
{
    const int t = blockIdx.x * blockDim.x + threadIdx.x;
    const int e = t >> 6, o = t & 63;
    if (e >= ET) return;
    float acc = 0.f;
#pragma unroll
    for (int k = 0; k < 64; ++k)
        acc = fmaf(ee[e * 64 + k], et[k * 64 + o], acc);
    out[t] = acc;
}

extern "C" void kernel_launch(void* const* d_in, const int* in_sizes, int n_in,
                              void* d_out, int out_size, void* d_ws, size_t ws_size,
                              hipStream_t stream) {
    const float* nf     = (const float*)d_in[0];
    const float* W      = (const float*)d_in[1];
    const float* a_pos  = (const float*)d_in[2];
    const float* a_neg  = (const float*)d_in[3];
    const float* ee     = (const float*)d_in[4];
    const float* et     = (const float*)d_in[5];
    const int* unique_nodes = (const int*)d_in[6];
    const int* row_unique   = (const int*)d_in[7];
    const int* pos_col  = (const int*)d_in[9];
    const int* neg_col  = (const int*)d_in[11];

    const int U    = in_sizes[6];
    const int N    = in_sizes[7];
    const int Epos = in_sizes[8];
    const int Eneg = in_sizes[10];
    const int H    = in_sizes[1] / (64 * 64);   // W is [H,64,64]
    const int DEGN = Eneg / N;                  // 16
    const int DEGP = Epos / N - 1;              // 16 (self edges appended)
    const int ET   = in_sizes[4] / 64;          // 32 edge types

    __hip_bfloat16* WhB = (__hip_bfloat16*)d_ws;
    const size_t whBytes = (((size_t)H * U * 64 * sizeof(__hip_bfloat16)) + 255) & ~(size_t)255;
    float4* sc = (float4*)((char*)d_ws + whBytes);
    float* out = (float*)d_out;

    dim3 g1((U + 4 * UPB - 1) / (4 * UPB), H);
    wh_kernel<<<g1, 256, 0, stream>>>(nf, W, a_pos, a_neg, unique_nodes, WhB, sc, U);
    agg_kernel<<<N, 64 * H, 0, stream>>>(row_unique, pos_col, neg_col, WhB, sc, out,
                                         N, U, DEGP, DEGN, H);
    edge_kernel<<<(ET * 64 + 255) / 256, 256, 0, stream>>>(ee, et, out + (size_t)N * H * 64, ET);
}

// Round 2
// 107.033 us; speedup vs baseline: 1.5448x; 1.5448x over previous
//
#include <hip/hip_runtime.h>
#include <hip/hip_bf16.h>
#include <math.h>

#define LRELU_ALPHA 0.2f

typedef __attribute__((ext_vector_type(8))) short bf16x8;
typedef __attribute__((ext_vector_type(4))) float f32x4;

__device__ __forceinline__ unsigned short f2bf(float f) {
    union { float f; unsigned u; } v; v.f = f;
    unsigned r = v.u + 0x7fffu + ((v.u >> 16) & 1u);
    return (unsigned short)(r >> 16);
}
__device__ __forceinline__ float bf2f(unsigned short s) {
    union { unsigned u; float f; } v; v.u = ((unsigned)s) << 16;
    return v.f;
}

// Kernel 0: Wt[h][n][k] = bf16(W[h][k][n])   (tiny: H*64*64 elements)
__global__ void wtrans_kernel(const float* __restrict__ W, unsigned short* __restrict__ Wt, int HE) {
    int t = blockIdx.x * blockDim.x + threadIdx.x;
    if (t >= HE) return;
    int h = t >> 12, n = (t >> 6) & 63, k = t & 63;
    Wt[t] = f2bf(W[(size_t)h * 4096 + k * 64 + n]);
}

// Kernel 1: MFMA Wh = gather(nf)[U,64] @ W[h][64,64] -> WhB bf16, plus fused
// per-(h,u) score dots {a_pos_dst, a_pos_src, a_neg_dst, a_neg_src}.Wh[u,:]
// One wave: 16 rows (u) x 64 cols, all H heads (A-frags reused across heads).
__global__ __launch_bounds__(256) void wh_mfma_kernel(
    const float* __restrict__ nf, const unsigned short* __restrict__ Wt,
    const float* __restrict__ a_pos, const float* __restrict__ a_neg,
    const int* __restrict__ unique_nodes,
    unsigned short* __restrict__ WhB, float4* __restrict__ sc, int U, int H)
{
    const int wave = threadIdx.x >> 6;
    const int lane = threadIdx.x & 63;
    const int grp  = lane >> 4;   // 0..3  -> k block
    const int r    = lane & 15;   // row within A-tile / col within B-tile
    const long u0  = ((long)blockIdx.x * 4 + wave) * 16;
    if (u0 >= U) return;

    const long ur = (u0 + r < U) ? (u0 + r) : (long)(U - 1);
    const float* erow = nf + (size_t)unique_nodes[ur] * 64 + grp * 8;
    bf16x8 a0, a1;
#pragma unroll
    for (int i = 0; i < 8; ++i) {
        a0[i] = (short)f2bf(erow[i]);        // k = grp*8 + i
        a1[i] = (short)f2bf(erow[32 + i]);   // k = 32 + grp*8 + i
    }

    for (int h = 0; h < H; ++h) {
        f32x4 acc[4];
#pragma unroll
        for (int nt = 0; nt < 4; ++nt) {
            acc[nt] = (f32x4)(0.f);
            const unsigned short* wp = Wt + (((size_t)h * 64 + nt * 16 + r) * 64 + grp * 8);
            bf16x8 b0 = *(const bf16x8*)wp;        // k = grp*8+i  (same mapping as A)
            bf16x8 b1 = *(const bf16x8*)(wp + 32); // k = 32+grp*8+i
            acc[nt] = __builtin_amdgcn_mfma_f32_16x16x32_bf16(a0, b0, acc[nt], 0, 0, 0);
            acc[nt] = __builtin_amdgcn_mfma_f32_16x16x32_bf16(a1, b1, acc[nt], 0, 0, 0);
        }
        // fused score dots; C/D layout: col = nt*16 + r, row = grp*4 + j
        float d0[4] = {0,0,0,0}, d1[4] = {0,0,0,0}, d2[4] = {0,0,0,0}, d3[4] = {0,0,0,0};
#pragma unroll
        for (int nt = 0; nt < 4; ++nt) {
            const int c = nt * 16 + r;
            const float apd = a_pos[h * 128 + c];
            const float aps = a_pos[h * 128 + 64 + c];
            const float and_ = a_neg[h * 128 + c];
            const float ans = a_neg[h * 128 + 64 + c];
#pragma unroll
            for (int j = 0; j < 4; ++j) {
                d0[j] = fmaf(acc[nt][j], apd, d0[j]);
                d1[j] = fmaf(acc[nt][j], aps, d1[j]);
                d2[j] = fmaf(acc[nt][j], and_, d2[j]);
                d3[j] = fmaf(acc[nt][j], ans, d3[j]);
            }
        }
#pragma unroll
        for (int j = 0; j < 4; ++j) {
#pragma unroll
            for (int off = 8; off; off >>= 1) {   // reduce across the 16-lane group
                d0[j] += __shfl_xor(d0[j], off, 64);
                d1[j] += __shfl_xor(d1[j], off, 64);
                d2[j] += __shfl_xor(d2[j], off, 64);
                d3[j] += __shfl_xor(d3[j], off, 64);
            }
        }
#pragma unroll
        for (int j = 0; j < 4; ++j) {
            const long u = u0 + grp * 4 + j;
            if (u < U) {
                if (r == 0) sc[(size_t)h * U + u] = make_float4(d0[j], d1[j], d2[j], d3[j]);
#pragma unroll
                for (int nt = 0; nt < 4; ++nt)
                    WhB[((size_t)h * U + u) * 64 + nt * 16 + r] = f2bf(acc[nt][j]);
            }
        }
    }
}

// Kernel 2: per (row, head) wave: 33-edge joint softmax + weighted gather-sum.
// DP/DN compile-time (>0) enables full unroll of the gather loop.
template <int DP, int DN>
__global__ __launch_bounds__(256) void agg_kernel(
    const int* __restrict__ row_unique,
    const int* __restrict__ pos_col, const int* __restrict__ neg_col,
    const unsigned short* __restrict__ WhB, const float4* __restrict__ sc,
    float* __restrict__ out, int N, int U, int rDP, int rDN, int H)
{
    const int DEGP = DP > 0 ? DP : rDP;
    const int DEGN = DN > 0 ? DN : rDN;
    const int NE   = DEGP + 1 + DEGN;

    const int i    = blockIdx.x;
    const int h    = threadIdx.x >> 6;
    const int lane = threadIdx.x & 63;

    __shared__ int   s_col[64];
    __shared__ float s_att[8][64];

    const float4* sch = sc + (size_t)h * U;
    const float4 scd = sch[row_unique[i]];   // .x = pos_dst, .z = neg_dst

    int col = 0;
    float score = -INFINITY;
    if (lane < NE) {
        if (lane < DEGP)       col = pos_col[(size_t)i * DEGP + lane];
        else if (lane == DEGP) col = pos_col[(size_t)N * DEGP + i];  // self edge
        else                   col = neg_col[(size_t)i * DEGN + (lane - DEGP - 1)];
        const float4 scs = sch[col];         // .y = pos_src, .w = neg_src
        const float raw = (lane <= DEGP) ? (scd.x + scs.y) : (scd.z + scs.w);
        score = (raw > 0.f) ? raw : LRELU_ALPHA * raw;
    }
    float m = score;
#pragma unroll
    for (int off = 32; off; off >>= 1) m = fmaxf(m, __shfl_xor(m, off, 64));
    const float ex = (lane < NE) ? __expf(score - m) : 0.f;
    float ssum = ex;
#pragma unroll
    for (int off = 32; off; off >>= 1) ssum += __shfl_xor(ssum, off, 64);
    const float att = ex / ssum;

    if (h == 0) s_col[lane] = col;
    s_att[h][lane] = att;
    __syncthreads();

    const unsigned short* wh = WhB + (size_t)h * U * 64;
    float acc = 0.f;
#pragma unroll
    for (int e = 0; e < NE; ++e) {
        const int   c = s_col[e];
        const float a = s_att[h][e];
        acc = fmaf(a, bf2f(wh[(size_t)c * 64 + lane]), acc);
    }
    out[(size_t)i * (H * 64) + h * 64 + lane] = fmaxf(acc, 0.f);
}

// Kernel 3: edge_out = edge_embedding @ edge_transform  ([ET,64] @ [64,64])
__global__ void edge_kernel(const float* __restrict__ ee, const float* __restrict__ et,
                            float* __restrict__ out, int ET)
{
    const int t = blockIdx.x * blockDim.x + threadIdx.x;
    const int e = t >> 6, o = t & 63;
    if (e >= ET) return;
    float acc = 0.f;
#pragma unroll
    for (int k = 0; k < 64; ++k)
        acc = fmaf(ee[e * 64 + k], et[k * 64 + o], acc);
    out[t] = acc;
}

extern "C" void kernel_launch(void* const* d_in, const int* in_sizes, int n_in,
                              void* d_out, int out_size, void* d_ws, size_t ws_size,
                              hipStream_t stream) {
    const float* nf     = (const float*)d_in[0];
    const float* W      = (const float*)d_in[1];
    const float* a_pos  = (const float*)d_in[2];
    const float* a_neg  = (const float*)d_in[3];
    const float* ee     = (const float*)d_in[4];
    const float* et     = (const float*)d_in[5];
    const int* unique_nodes = (const int*)d_in[6];
    const int* row_unique   = (const int*)d_in[7];
    const int* pos_col  = (const int*)d_in[9];
    const int* neg_col  = (const int*)d_in[11];

    const int U    = in_sizes[6];
    const int N    = in_sizes[7];
    const int Epos = in_sizes[8];
    const int Eneg = in_sizes[10];
    const int H    = in_sizes[1] / (64 * 64);   // W is [H,64,64]
    const int DEGN = Eneg / N;                  // 16
    const int DEGP = Epos / N - 1;              // 16 (self edges appended)
    const int ET   = in_sizes[4] / 64;          // 32 edge types

    unsigned short* WhB = (unsigned short*)d_ws;
    const size_t whBytes = (((size_t)H * U * 64 * sizeof(unsigned short)) + 255) & ~(size_t)255;
    float4* sc = (float4*)((char*)d_ws + whBytes);
    const size_t scBytes = (((size_t)H * U * sizeof(float4)) + 255) & ~(size_t)255;
    unsigned short* Wt = (unsigned short*)((char*)d_ws + whBytes + scBytes);
    float* out = (float*)d_out;

    const int HE = H * 64 * 64;
    wtrans_kernel<<<(HE + 255) / 256, 256, 0, stream>>>(W, Wt, HE);

    const int nwaves = (U + 15) / 16;
    wh_mfma_kernel<<<(nwaves + 3) / 4, 256, 0, stream>>>(nf, Wt, a_pos, a_neg,
                                                         unique_nodes, WhB, sc, U, H);

    if (DEGP == 16 && DEGN == 16)
        agg_kernel<16, 16><<<N, 64 * H, 0, stream>>>(row_unique, pos_col, neg_col, WhB, sc,
                                                     out, N, U, DEGP, DEGN, H);
    else
        agg_kernel<0, 0><<<N, 64 * H, 0, stream>>>(row_unique, pos_col, neg_col, WhB, sc,
                                                   out, N, U, DEGP, DEGN, H);

    edge_kernel<<<(ET * 64 + 255) / 256, 256, 0, stream>>>(ee, et, out + (size_t)N * H * 64, ET);
}